// Round 1
// baseline (437.825 us; speedup 1.0000x reference)
//
#include <hip/hip_runtime.h>
#include <math.h>

// Problem constants
#define N_ROWS   131072      // 32*64*64 pixels
#define DIM      64          // embedding dim
#define KCODES   1024        // codebook entries
#define HWSZ     4096        // 64*64
#define CHW      262144      // 64*64*64 (per-batch NCHW stride)
#define OUT_ELEMS 8388608    // 32*64*64*64
#define BLOCK    256
#define PIX      2           // pixels per thread: each LDS w-broadcast feeds 2 fma chains
#define PIXBLK   (BLOCK * PIX)        // 512 pixels per block
#define NBLOCKS  (N_ROWS / PIXBLK)    // 256 -> exactly 1 block/CU
#define TILE_K   256         // codes per LDS tile (64 KB)

// ---------------------------------------------------------------------------
// numpy pairwise sum of squares, n=64 (8-accumulator block, scalar order).
// Bit-exact np.sum(v**2, axis=-1); contract(off) keeps mul/add separate.
// ---------------------------------------------------------------------------
__device__ __forceinline__ float np_sumsq64(const float* v) {
#pragma clang fp contract(off)
    float r[8];
#pragma unroll
    for (int j = 0; j < 8; ++j) r[j] = v[j] * v[j];
#pragma unroll
    for (int i = 8; i < 64; i += 8) {
#pragma unroll
        for (int j = 0; j < 8; ++j) {
            float p = v[i + j] * v[i + j];
            r[j] = r[j] + p;
        }
    }
    float s01 = r[0] + r[1];
    float s23 = r[2] + r[3];
    float s45 = r[4] + r[5];
    float s67 = r[6] + r[7];
    return (s01 + s23) + (s45 + s67);
}

// ---------------------------------------------------------------------------
// Kernel 0: per-code ||w_k||^2 (numpy-pairwise) -> ws[0..1023]
// ---------------------------------------------------------------------------
__global__ __launch_bounds__(256) void vq_wsum(const float* __restrict__ w,
                                               float* __restrict__ wsum) {
    int k = blockIdx.x * blockDim.x + threadIdx.x;   // grid = 4*256 = 1024
    const float* wr = w + k * DIM;
    float wv[DIM];
#pragma unroll
    for (int d = 0; d < DIM; ++d) wv[d] = wr[d];
    wsum[k] = np_sumsq64(wv);
}

// ---------------------------------------------------------------------------
// Kernel 1: main VQ. TWO pixels per thread (x0,x1 in 128 VGPRs): every LDS
//   weight broadcast is reused by 2 fma chains -> LDS pipe traffic per fma
//   halves (it was the ~100%-busy resource; VALU was 72%).
//   4 independent fmaf chains/iter (2px x 2codes) cover dep latency at
//   1 wave/SIMD.
//   Numerics BIT-IDENTICAL per (pixel, code) to the passing kernel:
//     a  = np_sumsq64(x)
//     c  = sequential __builtin_fmaf chain d=0..63
//     dk = fl( fl(a+b_k) - 2*c ),  argmin strict < (ascending code order)
// ---------------------------------------------------------------------------
__global__ __launch_bounds__(256, 1) void vq_main(const float* __restrict__ inp,
                                                  const float* __restrict__ weight,
                                                  const float* __restrict__ wsum,
                                                  float* __restrict__ out,
                                                  float* __restrict__ idx_out,
                                                  float* __restrict__ block_loss) {
    __shared__ float sw[TILE_K * DIM];   // 64 KB weight tile
    __shared__ float sws[TILE_K];        // 1 KB  wsum tile
    __shared__ float red[BLOCK / 64];

    const int tid = threadIdx.x;
    const int n0  = blockIdx.x * PIXBLK + tid;   // grid exact: 256*256, x2 pixels
    const int n1  = n0 + BLOCK;
    const int b0 = n0 >> 12, hw0 = n0 & 4095;
    const int b1 = n1 >> 12, hw1 = n1 & 4095;

    const float* xb0 = inp + (size_t)b0 * CHW + hw0;
    const float* xb1 = inp + (size_t)b1 * CHW + hw1;
    float x0[DIM], x1[DIM];
#pragma unroll
    for (int d = 0; d < DIM; ++d) x0[d] = xb0[(size_t)d * HWSZ];
#pragma unroll
    for (int d = 0; d < DIM; ++d) x1[d] = xb1[(size_t)d * HWSZ];

    const float a0 = np_sumsq64(x0);
    const float a1 = np_sumsq64(x1);

    float best0 = 3.402823466e38f, best1 = 3.402823466e38f;
    int   bk0 = 0, bk1 = 0;

    for (int tile = 0; tile < KCODES; tile += TILE_K) {
        // ---- stage tile: 256 codes x 64 floats, coalesced float4 loads ----
        __syncthreads();   // protect previous tile's readers
        {
            const float4* gsrc = (const float4*)(weight + (size_t)tile * DIM);
            float4* ldst = (float4*)sw;
            // 16384 floats = 4096 float4; 256 threads -> 16 each
#pragma unroll
            for (int i = 0; i < 16; ++i)
                ldst[i * BLOCK + tid] = gsrc[i * BLOCK + tid];
            sws[tid] = wsum[tile + tid];
        }
        __syncthreads();

        // ---- sweep tile: 2 codes x 2 pixels = 4 independent chains ----
        for (int kk = 0; kk < TILE_K; kk += 2) {
            const float* wp0 = &sw[kk * DIM];
            const float* wp1 = wp0 + DIM;
            float c00 = 0.f, c01 = 0.f, c10 = 0.f, c11 = 0.f;
#pragma unroll
            for (int d = 0; d < DIM; ++d) {
                const float wa = wp0[d];
                const float wb = wp1[d];
                c00 = __builtin_fmaf(x0[d], wa, c00);
                c10 = __builtin_fmaf(x1[d], wa, c10);
                c01 = __builtin_fmaf(x0[d], wb, c01);
                c11 = __builtin_fmaf(x1[d], wb, c11);
            }
            float dk00, dk01, dk10, dk11;
            {
#pragma clang fp contract(off)
                const float sa = a0 + sws[kk];
                const float sb = a0 + sws[kk + 1];
                const float ta = a1 + sws[kk];
                const float tb = a1 + sws[kk + 1];
                dk00 = sa - 2.0f * c00;
                dk01 = sb - 2.0f * c01;
                dk10 = ta - 2.0f * c10;
                dk11 = tb - 2.0f * c11;
            }
            const int k0 = tile + kk;
            if (dk00 < best0) { best0 = dk00; bk0 = k0; }
            if (dk01 < best0) { best0 = dk01; bk0 = k0 + 1; }
            if (dk10 < best1) { best1 = dk10; bk1 = k0; }
            if (dk11 < best1) { best1 = dk11; bk1 = k0 + 1; }
        }
    }

    // Epilogue: gather winning code rows, write out (coalesced), loss partials.
    const float* wb0 = weight + bk0 * DIM;   // per-lane gather, L2-hot
    const float* wb1 = weight + bk1 * DIM;
    float* ob0 = out + (size_t)b0 * CHW + hw0;
    float* ob1 = out + (size_t)b1 * CHW + hw1;
    float ls0 = 0.f, ls1 = 0.f;
#pragma unroll
    for (int c = 0; c < DIM; ++c) {
        const float wv0 = wb0[c];
        ob0[(size_t)c * HWSZ] = wv0;
        const float d0 = wv0 - x0[c];
        ls0 = fmaf(d0, d0, ls0);
        const float wv1 = wb1[c];
        ob1[(size_t)c * HWSZ] = wv1;
        const float d1 = wv1 - x1[c];
        ls1 = fmaf(d1, d1, ls1);
    }
    idx_out[n0] = (float)bk0;
    idx_out[n1] = (float)bk1;

    // Block reduction of loss partial (4 waves of 64)
    float ls = ls0 + ls1;
#pragma unroll
    for (int off = 32; off > 0; off >>= 1) ls += __shfl_down(ls, off, 64);
    const int lane = tid & 63;
    const int wid  = tid >> 6;
    if (lane == 0) red[wid] = ls;
    __syncthreads();
    if (tid == 0)
        block_loss[blockIdx.x] = (red[0] + red[1]) + (red[2] + red[3]);
}

// ---------------------------------------------------------------------------
// Kernel 2: reduce 256 block partials -> loss scalar
//   loss = q + 0.25*e = 1.25 * mean((quantized - x)^2)
// ---------------------------------------------------------------------------
__global__ __launch_bounds__(256) void vq_loss_reduce(const float* __restrict__ bl,
                                                      float* __restrict__ loss_out) {
    double s = 0.0;
    for (int i = threadIdx.x; i < NBLOCKS; i += BLOCK) s += (double)bl[i];
    __shared__ double red[BLOCK / 64];
#pragma unroll
    for (int off = 32; off > 0; off >>= 1) s += __shfl_down(s, off, 64);
    const int lane = threadIdx.x & 63;
    const int wid  = threadIdx.x >> 6;
    if (lane == 0) red[wid] = s;
    __syncthreads();
    if (threadIdx.x == 0) {
        const double total = (red[0] + red[1]) + (red[2] + red[3]);
        loss_out[0] = (float)(1.25 * total / (double)OUT_ELEMS);
    }
}

// ---------------------------------------------------------------------------
extern "C" void kernel_launch(void* const* d_in, const int* in_sizes, int n_in,
                              void* d_out, int out_size, void* d_ws, size_t ws_size,
                              hipStream_t stream) {
    const float* inp    = (const float*)d_in[0];   // [32,64,64,64] NCHW fp32
    const float* weight = (const float*)d_in[1];   // [1024,64] fp32

    float* out_q    = (float*)d_out;                         // 8388608 elems
    float* out_loss = (float*)d_out + OUT_ELEMS;             // 1 elem
    float* out_idx  = (float*)d_out + OUT_ELEMS + 1;         // 131072 elems

    float* wsum       = (float*)d_ws;                        // 1024 floats
    float* block_loss = (float*)d_ws + KCODES;               // 256 floats

    vq_wsum<<<KCODES / 256, 256, 0, stream>>>(weight, wsum);
    vq_main<<<NBLOCKS, BLOCK, 0, stream>>>(inp, weight, wsum,
                                           out_q, out_idx, block_loss);
    vq_loss_reduce<<<1, BLOCK, 0, stream>>>(block_loss, out_loss);
}

// Round 2
// 331.175 us; speedup vs baseline: 1.3220x; 1.3220x over previous
//
#include <hip/hip_runtime.h>
#include <math.h>

// Problem constants
#define N_ROWS   131072      // 32*64*64 pixels
#define DIM      64          // embedding dim
#define KCODES   1024        // codebook entries
#define HWSZ     4096        // 64*64
#define CHW      262144      // 64*64*64 (per-batch NCHW stride)
#define OUT_ELEMS 8388608    // 32*64*64*64
#define BLOCK    512         // 8 waves: halves split the codebook (split-K)
#define HALF_T   256         // threads per half
#define PIX      2           // pixels per thread: each LDS w-broadcast feeds 2 fma chains
#define PIXBLK   (HALF_T * PIX)       // 512 pixels per block
#define NBLOCKS  (N_ROWS / PIXBLK)    // 256 -> exactly 1 block/CU, 8 waves = 2/SIMD
#define KHALF    512         // codes per half
#define TILE_K   128         // codes per LDS tile per half (32 KB each, 2 live)

// ---------------------------------------------------------------------------
// numpy pairwise sum of squares, n=64 (8-accumulator block, scalar order).
// Bit-exact np.sum(v**2, axis=-1); contract(off) keeps mul/add separate.
// ---------------------------------------------------------------------------
__device__ __forceinline__ float np_sumsq64(const float* v) {
#pragma clang fp contract(off)
    float r[8];
#pragma unroll
    for (int j = 0; j < 8; ++j) r[j] = v[j] * v[j];
#pragma unroll
    for (int i = 8; i < 64; i += 8) {
#pragma unroll
        for (int j = 0; j < 8; ++j) {
            float p = v[i + j] * v[i + j];
            r[j] = r[j] + p;
        }
    }
    float s01 = r[0] + r[1];
    float s23 = r[2] + r[3];
    float s45 = r[4] + r[5];
    float s67 = r[6] + r[7];
    return (s01 + s23) + (s45 + s67);
}

// ---------------------------------------------------------------------------
// Kernel 0: per-code ||w_k||^2 (numpy-pairwise) -> ws[0..1023]
// ---------------------------------------------------------------------------
__global__ __launch_bounds__(256) void vq_wsum(const float* __restrict__ w,
                                               float* __restrict__ wsum) {
    int k = blockIdx.x * blockDim.x + threadIdx.x;   // grid = 4*256 = 1024
    const float* wr = w + k * DIM;
    float wv[DIM];
#pragma unroll
    for (int d = 0; d < DIM; ++d) wv[d] = wr[d];
    wsum[k] = np_sumsq64(wv);
}

// ---------------------------------------------------------------------------
// Kernel 1: main VQ.
//   - 2 pixels/thread: each LDS weight broadcast feeds 2 fma chains (halves
//     LDS pipe traffic per fma; 4 independent chains enable v_pk_fma_f32).
//   - split-K across block halves: threads t and t+256 own the SAME 2 pixels;
//     lower half sweeps codes 0..511, upper half 512..1023. This restores
//     2 waves/SIMD (round-1's 1 wave/SIMD exposed LDS latency: VALU 41%).
//   - combine: upper keeps its own winner only if strictly smaller, else
//     takes lower's -> exact "first index of min" semantics.
//   Numerics BIT-IDENTICAL per (pixel, code) to the passing kernel:
//     a  = np_sumsq64(x)
//     c  = sequential __builtin_fmaf chain d=0..63
//     dk = fl( fl(a+b_k) - 2*c ),  argmin strict < (ascending code order)
// ---------------------------------------------------------------------------
__global__ __launch_bounds__(512, 1) void vq_main(const float* __restrict__ inp,
                                                  const float* __restrict__ weight,
                                                  const float* __restrict__ wsum,
                                                  float* __restrict__ out,
                                                  float* __restrict__ idx_out,
                                                  float* __restrict__ block_loss) {
    __shared__ float sw[2][TILE_K * DIM];   // 2 x 32 KB weight tiles (one per half)
    __shared__ float sws[2][TILE_K];        // wsum tiles
    __shared__ float cbv[2][HALF_T];        // lower half's best values
    __shared__ int   cbk[2][HALF_T];        // lower half's best indices
    __shared__ float red[BLOCK / 64];

    const int tid  = threadIdx.x;
    const int half = tid >> 8;        // 0 = codes 0..511, 1 = codes 512..1023
    const int t    = tid & 255;
    const int n0   = blockIdx.x * PIXBLK + t;
    const int n1   = n0 + HALF_T;
    const int b0 = n0 >> 12, hw0 = n0 & 4095;
    const int b1 = n1 >> 12, hw1 = n1 & 4095;

    const float* xb0 = inp + (size_t)b0 * CHW + hw0;
    const float* xb1 = inp + (size_t)b1 * CHW + hw1;
    float x0[DIM], x1[DIM];
#pragma unroll
    for (int d = 0; d < DIM; ++d) x0[d] = xb0[(size_t)d * HWSZ];
#pragma unroll
    for (int d = 0; d < DIM; ++d) x1[d] = xb1[(size_t)d * HWSZ];

    const float a0 = np_sumsq64(x0);
    const float a1 = np_sumsq64(x1);

    float best0 = 3.402823466e38f, best1 = 3.402823466e38f;
    int   bk0 = 0, bk1 = 0;

    const int kbase = half * KHALF;

    for (int tile = 0; tile < KHALF; tile += TILE_K) {
        // ---- stage this half's tile: 128 codes x 64 floats, float4 loads ----
        __syncthreads();   // protect previous tile's readers (both halves)
        {
            const float4* gsrc = (const float4*)(weight + (size_t)(kbase + tile) * DIM);
            float4* ldst = (float4*)sw[half];
            // 8192 floats = 2048 float4; 256 threads/half -> 8 each
#pragma unroll
            for (int i = 0; i < 8; ++i)
                ldst[i * HALF_T + t] = gsrc[i * HALF_T + t];
            if (t < TILE_K) sws[half][t] = wsum[kbase + tile + t];
        }
        __syncthreads();

        // ---- sweep tile: 2 codes x 2 pixels = 4 independent chains ----
        for (int kk = 0; kk < TILE_K; kk += 2) {
            const float* wp0 = &sw[half][kk * DIM];
            const float* wp1 = wp0 + DIM;
            float c00 = 0.f, c01 = 0.f, c10 = 0.f, c11 = 0.f;
#pragma unroll
            for (int d = 0; d < DIM; ++d) {
                const float wa = wp0[d];
                const float wb = wp1[d];
                c00 = __builtin_fmaf(x0[d], wa, c00);
                c10 = __builtin_fmaf(x1[d], wa, c10);
                c01 = __builtin_fmaf(x0[d], wb, c01);
                c11 = __builtin_fmaf(x1[d], wb, c11);
            }
            float dk00, dk01, dk10, dk11;
            {
#pragma clang fp contract(off)
                const float sa = a0 + sws[half][kk];
                const float sb = a0 + sws[half][kk + 1];
                const float ta = a1 + sws[half][kk];
                const float tb = a1 + sws[half][kk + 1];
                dk00 = sa - 2.0f * c00;
                dk01 = sb - 2.0f * c01;
                dk10 = ta - 2.0f * c10;
                dk11 = tb - 2.0f * c11;
            }
            const int k0 = kbase + tile + kk;
            if (dk00 < best0) { best0 = dk00; bk0 = k0; }
            if (dk01 < best0) { best0 = dk01; bk0 = k0 + 1; }
            if (dk10 < best1) { best1 = dk10; bk1 = k0; }
            if (dk11 < best1) { best1 = dk11; bk1 = k0 + 1; }
        }
    }

    // ---- combine halves: lower publishes, upper resolves ----
    __syncthreads();
    if (half == 0) {
        cbv[0][t] = best0; cbk[0][t] = bk0;
        cbv[1][t] = best1; cbk[1][t] = bk1;
    }
    __syncthreads();

    float ls = 0.f;
    if (half == 1) {
        // upper wins only if strictly smaller (lower indices take ties)
        const float lo0 = cbv[0][t]; const int lk0 = cbk[0][t];
        const float lo1 = cbv[1][t]; const int lk1 = cbk[1][t];
        if (!(best0 < lo0)) { best0 = lo0; bk0 = lk0; }
        if (!(best1 < lo1)) { best1 = lo1; bk1 = lk1; }

        // Epilogue: gather winning code rows, write out, loss partials.
        const float* wb0 = weight + bk0 * DIM;   // per-lane gather, L2-hot
        const float* wb1 = weight + bk1 * DIM;
        float* ob0 = out + (size_t)b0 * CHW + hw0;
        float* ob1 = out + (size_t)b1 * CHW + hw1;
#pragma unroll
        for (int c = 0; c < DIM; ++c) {
            const float wv0 = wb0[c];
            ob0[(size_t)c * HWSZ] = wv0;
            const float d0 = wv0 - x0[c];
            ls = fmaf(d0, d0, ls);
            const float wv1 = wb1[c];
            ob1[(size_t)c * HWSZ] = wv1;
            const float d1 = wv1 - x1[c];
            ls = fmaf(d1, d1, ls);
        }
        idx_out[n0] = (float)bk0;
        idx_out[n1] = (float)bk1;
    }

    // Block reduction of loss partial (8 waves; lower waves contribute 0)
#pragma unroll
    for (int off = 32; off > 0; off >>= 1) ls += __shfl_down(ls, off, 64);
    const int lane = tid & 63;
    const int wid  = tid >> 6;
    if (lane == 0) red[wid] = ls;
    __syncthreads();
    if (tid == 0) {
        float s = 0.f;
#pragma unroll
        for (int w = 0; w < BLOCK / 64; ++w) s += red[w];
        block_loss[blockIdx.x] = s;
    }
}

// ---------------------------------------------------------------------------
// Kernel 2: reduce 256 block partials -> loss scalar
//   loss = q + 0.25*e = 1.25 * mean((quantized - x)^2)
// ---------------------------------------------------------------------------
__global__ __launch_bounds__(256) void vq_loss_reduce(const float* __restrict__ bl,
                                                      float* __restrict__ loss_out) {
    double s = 0.0;
    for (int i = threadIdx.x; i < NBLOCKS; i += 256) s += (double)bl[i];
    __shared__ double red[4];
#pragma unroll
    for (int off = 32; off > 0; off >>= 1) s += __shfl_down(s, off, 64);
    const int lane = threadIdx.x & 63;
    const int wid  = threadIdx.x >> 6;
    if (lane == 0) red[wid] = s;
    __syncthreads();
    if (threadIdx.x == 0) {
        const double total = (red[0] + red[1]) + (red[2] + red[3]);
        loss_out[0] = (float)(1.25 * total / (double)OUT_ELEMS);
    }
}

// ---------------------------------------------------------------------------
extern "C" void kernel_launch(void* const* d_in, const int* in_sizes, int n_in,
                              void* d_out, int out_size, void* d_ws, size_t ws_size,
                              hipStream_t stream) {
    const float* inp    = (const float*)d_in[0];   // [32,64,64,64] NCHW fp32
    const float* weight = (const float*)d_in[1];   // [1024,64] fp32

    float* out_q    = (float*)d_out;                         // 8388608 elems
    float* out_loss = (float*)d_out + OUT_ELEMS;             // 1 elem
    float* out_idx  = (float*)d_out + OUT_ELEMS + 1;         // 131072 elems

    float* wsum       = (float*)d_ws;                        // 1024 floats
    float* block_loss = (float*)d_ws + KCODES;               // 256 floats

    vq_wsum<<<KCODES / 256, 256, 0, stream>>>(weight, wsum);
    vq_main<<<NBLOCKS, BLOCK, 0, stream>>>(inp, weight, wsum,
                                           out_q, out_idx, block_loss);
    vq_loss_reduce<<<1, BLOCK / 2, 0, stream>>>(block_loss, out_loss);
}

// Round 3
// 313.569 us; speedup vs baseline: 1.3963x; 1.0561x over previous
//
#include <hip/hip_runtime.h>
#include <math.h>

// Problem constants
#define N_ROWS   131072      // 32*64*64 pixels
#define DIM      64          // embedding dim
#define KCODES   1024        // codebook entries
#define HWSZ     4096        // 64*64
#define CHW      262144      // 64*64*64 (per-batch NCHW stride)
#define OUT_ELEMS 8388608    // 32*64*64*64
#define BLOCK    512         // 8 waves: halves split the codebook (split-K)
#define HALF_T   256         // threads per half
#define PIX      2           // pixels per thread: each LDS w-broadcast feeds 2 fma chains
#define PIXBLK   (HALF_T * PIX)       // 512 pixels per block
#define NBLOCKS  (N_ROWS / PIXBLK)    // 256 -> exactly 1 block/CU, 8 waves = 2/SIMD
#define KHALF    512         // codes per half
#define TILE_K   256         // codes per LDS tile per half (64 KB each, 2 live)
#define TILE_PAD (TILE_K + 2) // +2 pad rows: pipeline prefetch overruns tile end

// ---------------------------------------------------------------------------
// numpy pairwise sum of squares, n=64 (8-accumulator block, scalar order).
// Bit-exact np.sum(v**2, axis=-1); contract(off) keeps mul/add separate.
// ---------------------------------------------------------------------------
__device__ __forceinline__ float np_sumsq64(const float* v) {
#pragma clang fp contract(off)
    float r[8];
#pragma unroll
    for (int j = 0; j < 8; ++j) r[j] = v[j] * v[j];
#pragma unroll
    for (int i = 8; i < 64; i += 8) {
#pragma unroll
        for (int j = 0; j < 8; ++j) {
            float p = v[i + j] * v[i + j];
            r[j] = r[j] + p;
        }
    }
    float s01 = r[0] + r[1];
    float s23 = r[2] + r[3];
    float s45 = r[4] + r[5];
    float s67 = r[6] + r[7];
    return (s01 + s23) + (s45 + s67);
}

// ---------------------------------------------------------------------------
// Kernel 0: per-code ||w_k||^2 (numpy-pairwise) -> ws[0..1023]
// ---------------------------------------------------------------------------
__global__ __launch_bounds__(256) void vq_wsum(const float* __restrict__ w,
                                               float* __restrict__ wsum) {
    int k = blockIdx.x * blockDim.x + threadIdx.x;   // grid = 4*256 = 1024
    const float* wr = w + k * DIM;
    float wv[DIM];
#pragma unroll
    for (int d = 0; d < DIM; ++d) wv[d] = wr[d];
    wsum[k] = np_sumsq64(wv);
}

// ---------------------------------------------------------------------------
// Software-pipeline helpers: 16-d "quarter" of a code pair lives in 8 float4
// registers; load the NEXT quarter while fma-ing the CURRENT one.
// ---------------------------------------------------------------------------
__device__ __forceinline__ void loadq(const float4* __restrict__ swv,
                                      int kka, int kkb, int q,
                                      float4 (&r0)[4], float4 (&r1)[4]) {
#pragma unroll
    for (int j = 0; j < 4; ++j) {
        r0[j] = swv[kka * 16 + q * 4 + j];
        r1[j] = swv[kkb * 16 + q * 4 + j];
    }
}

// fma over 16 dims (db..db+15). Per-chain accumulation order is d ascending:
// quarters are consumed in order db = 0,16,32,48 -> BIT-IDENTICAL to the
// sequential d=0..63 __builtin_fmaf chain of the passing kernel.
__device__ __forceinline__ void fma16(const float4 (&r0)[4], const float4 (&r1)[4],
                                      const float* __restrict__ x0,
                                      const float* __restrict__ x1, int db,
                                      float& c00, float& c01,
                                      float& c10, float& c11) {
#pragma unroll
    for (int j = 0; j < 4; ++j) {
        const float4 va = r0[j];
        const float4 vb = r1[j];
        const int d = db + j * 4;
        c00 = __builtin_fmaf(x0[d + 0], va.x, c00); c10 = __builtin_fmaf(x1[d + 0], va.x, c10);
        c01 = __builtin_fmaf(x0[d + 0], vb.x, c01); c11 = __builtin_fmaf(x1[d + 0], vb.x, c11);
        c00 = __builtin_fmaf(x0[d + 1], va.y, c00); c10 = __builtin_fmaf(x1[d + 1], va.y, c10);
        c01 = __builtin_fmaf(x0[d + 1], vb.y, c01); c11 = __builtin_fmaf(x1[d + 1], vb.y, c11);
        c00 = __builtin_fmaf(x0[d + 2], va.z, c00); c10 = __builtin_fmaf(x1[d + 2], va.z, c10);
        c01 = __builtin_fmaf(x0[d + 2], vb.z, c01); c11 = __builtin_fmaf(x1[d + 2], vb.z, c11);
        c00 = __builtin_fmaf(x0[d + 3], va.w, c00); c10 = __builtin_fmaf(x1[d + 3], va.w, c10);
        c01 = __builtin_fmaf(x0[d + 3], vb.w, c01); c11 = __builtin_fmaf(x1[d + 3], vb.w, c11);
    }
}

// ---------------------------------------------------------------------------
// Kernel 1: main VQ.
//   - 2 pixels/thread: each LDS weight broadcast feeds 2 fma chains.
//   - split-K across block halves (codes 0..511 / 512..1023), 8 waves/CU.
//   - d-quarter software pipeline: prefetch next 16-d quarter (8 float4)
//     while fma-ing current -> shallow steady LDS queue instead of 32-read
//     bursts (diagnosed ~600-cy exposed queue delay per iteration).
//   - TILE_K=256: only 2 staging barriers per half.
//   Numerics BIT-IDENTICAL per (pixel, code):
//     a  = np_sumsq64(x)
//     c  = sequential __builtin_fmaf chain d=0..63
//     dk = fl( fl(a+b_k) - 2*c ),  argmin strict < (ascending code order)
// ---------------------------------------------------------------------------
__global__ __launch_bounds__(512, 2) void vq_main(const float* __restrict__ inp,
                                                  const float* __restrict__ weight,
                                                  const float* __restrict__ wsum,
                                                  float* __restrict__ out,
                                                  float* __restrict__ idx_out,
                                                  float* __restrict__ block_loss) {
    __shared__ float sw[2][TILE_PAD * DIM];  // 2 x 64.5 KB weight tiles
    __shared__ float sws[2][TILE_K];         // wsum tiles
    __shared__ float cbv[2][HALF_T];         // lower half's best values
    __shared__ int   cbk[2][HALF_T];         // lower half's best indices
    __shared__ float red[BLOCK / 64];

    const int tid  = threadIdx.x;
    const int half = tid >> 8;        // 0 = codes 0..511, 1 = codes 512..1023
    const int t    = tid & 255;
    const int n0   = blockIdx.x * PIXBLK + t;
    const int n1   = n0 + HALF_T;
    const int b0 = n0 >> 12, hw0 = n0 & 4095;
    const int b1 = n1 >> 12, hw1 = n1 & 4095;

    const float* xb0 = inp + (size_t)b0 * CHW + hw0;
    const float* xb1 = inp + (size_t)b1 * CHW + hw1;
    float x0[DIM], x1[DIM];
#pragma unroll
    for (int d = 0; d < DIM; ++d) x0[d] = xb0[(size_t)d * HWSZ];
#pragma unroll
    for (int d = 0; d < DIM; ++d) x1[d] = xb1[(size_t)d * HWSZ];

    const float a0 = np_sumsq64(x0);
    const float a1 = np_sumsq64(x1);

    float best0 = 3.402823466e38f, best1 = 3.402823466e38f;
    int   bk0 = 0, bk1 = 0;

    const int kbase = half * KHALF;
    const float4* swv = (const float4*)(&sw[half][0]);

    for (int tile = 0; tile < KHALF; tile += TILE_K) {
        // ---- stage tile: 256 codes x 64 floats, coalesced float4 loads ----
        __syncthreads();   // protect previous tile's readers (both halves)
        {
            const float4* gsrc = (const float4*)(weight + (size_t)(kbase + tile) * DIM);
            float4* ldst = (float4*)(&sw[half][0]);
            // 16384 floats = 4096 float4; 256 threads/half -> 16 each
#pragma unroll
            for (int i = 0; i < 16; ++i)
                ldst[i * HALF_T + t] = gsrc[i * HALF_T + t];
            sws[half][t] = wsum[kbase + tile + t];
        }
        __syncthreads();

        // ---- sweep tile: 2 codes x 2 pixels, d-quarter software pipeline ----
        float4 A0[4], A1[4], B0[4], B1[4];
        loadq(swv, 0, 1, 0, A0, A1);   // preload quarter 0 of code pair (0,1)

#pragma unroll 1
        for (int kk = 0; kk < TILE_K; kk += 2) {
            const float bsw0 = sws[half][kk];
            const float bsw1 = sws[half][kk + 1];
            float c00 = 0.f, c01 = 0.f, c10 = 0.f, c11 = 0.f;

            loadq(swv, kk, kk + 1, 1, B0, B1);      // prefetch q1
            fma16(A0, A1, x0, x1, 0,  c00, c01, c10, c11);
            loadq(swv, kk, kk + 1, 2, A0, A1);      // prefetch q2
            fma16(B0, B1, x0, x1, 16, c00, c01, c10, c11);
            loadq(swv, kk, kk + 1, 3, B0, B1);      // prefetch q3
            fma16(A0, A1, x0, x1, 32, c00, c01, c10, c11);
            loadq(swv, kk + 2, kk + 3, 0, A0, A1);  // prefetch next pair q0 (pad rows at tile end)
            fma16(B0, B1, x0, x1, 48, c00, c01, c10, c11);

            float dk00, dk01, dk10, dk11;
            {
#pragma clang fp contract(off)
                const float sa = a0 + bsw0;
                const float sb = a0 + bsw1;
                const float ta = a1 + bsw0;
                const float tb = a1 + bsw1;
                dk00 = sa - 2.0f * c00;
                dk01 = sb - 2.0f * c01;
                dk10 = ta - 2.0f * c10;
                dk11 = tb - 2.0f * c11;
            }
            const int k0 = kbase + tile + kk;
            if (dk00 < best0) { best0 = dk00; bk0 = k0; }
            if (dk01 < best0) { best0 = dk01; bk0 = k0 + 1; }
            if (dk10 < best1) { best1 = dk10; bk1 = k0; }
            if (dk11 < best1) { best1 = dk11; bk1 = k0 + 1; }
        }
    }

    // ---- combine halves: lower publishes, upper resolves ----
    __syncthreads();
    if (half == 0) {
        cbv[0][t] = best0; cbk[0][t] = bk0;
        cbv[1][t] = best1; cbk[1][t] = bk1;
    }
    __syncthreads();

    float ls = 0.f;
    if (half == 1) {
        // upper wins only if strictly smaller (lower indices take ties)
        const float lo0 = cbv[0][t]; const int lk0 = cbk[0][t];
        const float lo1 = cbv[1][t]; const int lk1 = cbk[1][t];
        if (!(best0 < lo0)) { best0 = lo0; bk0 = lk0; }
        if (!(best1 < lo1)) { best1 = lo1; bk1 = lk1; }

        // Epilogue: gather winning code rows, write out, loss partials.
        const float* wb0 = weight + bk0 * DIM;   // per-lane gather, L2-hot
        const float* wb1 = weight + bk1 * DIM;
        float* ob0 = out + (size_t)b0 * CHW + hw0;
        float* ob1 = out + (size_t)b1 * CHW + hw1;
#pragma unroll
        for (int c = 0; c < DIM; ++c) {
            const float wv0 = wb0[c];
            ob0[(size_t)c * HWSZ] = wv0;
            const float d0 = wv0 - x0[c];
            ls = fmaf(d0, d0, ls);
            const float wv1 = wb1[c];
            ob1[(size_t)c * HWSZ] = wv1;
            const float d1 = wv1 - x1[c];
            ls = fmaf(d1, d1, ls);
        }
        idx_out[n0] = (float)bk0;
        idx_out[n1] = (float)bk1;
    }

    // Block reduction of loss partial (8 waves; lower waves contribute 0)
#pragma unroll
    for (int off = 32; off > 0; off >>= 1) ls += __shfl_down(ls, off, 64);
    const int lane = tid & 63;
    const int wid  = tid >> 6;
    if (lane == 0) red[wid] = ls;
    __syncthreads();
    if (tid == 0) {
        float s = 0.f;
#pragma unroll
        for (int w = 0; w < BLOCK / 64; ++w) s += red[w];
        block_loss[blockIdx.x] = s;
    }
}

// ---------------------------------------------------------------------------
// Kernel 2: reduce 256 block partials -> loss scalar
//   loss = q + 0.25*e = 1.25 * mean((quantized - x)^2)
// ---------------------------------------------------------------------------
__global__ __launch_bounds__(256) void vq_loss_reduce(const float* __restrict__ bl,
                                                      float* __restrict__ loss_out) {
    double s = 0.0;
    for (int i = threadIdx.x; i < NBLOCKS; i += 256) s += (double)bl[i];
    __shared__ double red[4];
#pragma unroll
    for (int off = 32; off > 0; off >>= 1) s += __shfl_down(s, off, 64);
    const int lane = threadIdx.x & 63;
    const int wid  = threadIdx.x >> 6;
    if (lane == 0) red[wid] = s;
    __syncthreads();
    if (threadIdx.x == 0) {
        const double total = (red[0] + red[1]) + (red[2] + red[3]);
        loss_out[0] = (float)(1.25 * total / (double)OUT_ELEMS);
    }
}

// ---------------------------------------------------------------------------
extern "C" void kernel_launch(void* const* d_in, const int* in_sizes, int n_in,
                              void* d_out, int out_size, void* d_ws, size_t ws_size,
                              hipStream_t stream) {
    const float* inp    = (const float*)d_in[0];   // [32,64,64,64] NCHW fp32
    const float* weight = (const float*)d_in[1];   // [1024,64] fp32

    float* out_q    = (float*)d_out;                         // 8388608 elems
    float* out_loss = (float*)d_out + OUT_ELEMS;             // 1 elem
    float* out_idx  = (float*)d_out + OUT_ELEMS + 1;         // 131072 elems

    float* wsum       = (float*)d_ws;                        // 1024 floats
    float* block_loss = (float*)d_ws + KCODES;               // 256 floats

    vq_wsum<<<KCODES / 256, 256, 0, stream>>>(weight, wsum);
    vq_main<<<NBLOCKS, BLOCK, 0, stream>>>(inp, weight, wsum,
                                           out_q, out_idx, block_loss);
    vq_loss_reduce<<<1, BLOCK / 2, 0, stream>>>(block_loss, out_loss);
}